// Round 7
// baseline (193.195 us; speedup 1.0000x reference)
//
#include <hip/hip_runtime.h>

// ---------------------------------------------------------------------------
// ANHPMultiHeadAttention: fused QKV projection + exp-scored causal attention
// B=8, S=1024, FEAT=HID=1024, H=8, DH=128.
//
// R12 changes vs R11:
//  - Evidence: R11 (8x16-row waves, 4 waves/SIMD) WIN 198->193. attn now
//    ~35us, sub-top-5. Per-wave-iter VALU model: hand-rolled f2b RNE pack
//    ~160 cyc vs exp ~64 + MFMA ~160 -> packing is the largest VALU term.
//  - attn: P-pack via v_cvt_pk_bf16_f32 (1 inst per f32 pair, RNE -- bit-
//    identical to f2b) -> ~8 insts/wave-iter instead of ~80.
//  - prep: cast part fattened to 2 float4/thread (4096 blocks, was 8192).
//  - GEMM: R5 verbatim (control, 69.6-73.6us band). attn otherwise R11.
// ---------------------------------------------------------------------------

typedef __bf16 bf16x8 __attribute__((ext_vector_type(8)));
typedef float floatx4 __attribute__((ext_vector_type(4)));
typedef unsigned short u16;
typedef unsigned int u32;

#define RSCALE 0.08838834764831845f   // 1/sqrt(128)

__device__ __forceinline__ u16 f2b(float f) {       // fp32 -> bf16 bits, RNE
  union { float f; unsigned u; } v; v.f = f;
  return (u16)((v.u + 0x7FFFu + ((v.u >> 16) & 1u)) >> 16);
}

__device__ __forceinline__ u32 cvtpk_bf16(float lo, float hi) {
  u32 r;                               // r = bf16(lo) | bf16(hi)<<16, RNE
  asm("v_cvt_pk_bf16_f32 %0, %1, %2" : "=v"(r) : "v"(lo), "v"(hi));
  return r;
}

// async global->LDS, 16B per lane. LDS dst = wave-uniform base + lane*16.
__device__ __forceinline__ void gld_lds16(const void* g, void* l) {
  __builtin_amdgcn_global_load_lds(
      (const __attribute__((address_space(1))) unsigned*)g,
      (__attribute__((address_space(3))) unsigned*)l, 16, 0, 0);
}

#define MFMA16(a, b, c) __builtin_amdgcn_mfma_f32_16x16x32_bf16(a, b, c, 0, 0, 0)

// ---------------------------------------------------------------------------
// Kernel 1: prep = cast X (blocks 0..4095, 2 float4/thread) + transpose W
// (blocks 4096..7167)
// ---------------------------------------------------------------------------
__global__ __launch_bounds__(256) void prep_kernel(
    const float4* __restrict__ X, u16* __restrict__ Xb,
    const float* __restrict__ Wq, const float* __restrict__ Wk,
    const float* __restrict__ Wv, u16* __restrict__ Wtb) {
  if (blockIdx.x < 4096) {
#pragma unroll
    for (int rep = 0; rep < 2; ++rep) {
      unsigned i = blockIdx.x * 512u + rep * 256u + threadIdx.x;
      float4 v = X[i];
      ushort4 o;
      o.x = f2b(v.x); o.y = f2b(v.y); o.z = f2b(v.z); o.w = f2b(v.w);
      *reinterpret_cast<ushort4*>(Xb + 4u * i) = o;
    }
  } else {
    const int bid = blockIdx.x - 4096;          // 0..3071
    const int mat = bid >> 10;                  // 1024 blocks per matrix
    const int bx = bid & 31, by = (bid >> 5) & 31;
    const float* W = (mat == 0) ? Wq : (mat == 1) ? Wk : Wv;
    u16* Wt = Wtb + (size_t)mat * (1024u * 1024u);
    __shared__ u16 tile[32][33];
    const int x = threadIdx.x & 31, y = threadIdx.x >> 5;
    const int kt = bx * 32, nt = by * 32;
#pragma unroll
    for (int i = 0; i < 4; ++i)
      tile[y + 8 * i][x] = f2b(W[(size_t)(kt + y + 8 * i) * 1024 + nt + x]);
    __syncthreads();
#pragma unroll
    for (int i = 0; i < 4; ++i)
      Wt[(size_t)(nt + y + 8 * i) * 1024 + kt + x] = tile[x][y + 8 * i];
  }
}

// ---------------------------------------------------------------------------
// Kernel 2: QKV GEMM (R5-proven). 128x128 tile, BK=64 (128B rows, xor8
// swizzle, 0 conflicts), double-buffered single-barrier pipeline.
// grid (64,8,3). Q,K stored [B,H,S,DH]; V stored [B,H,DH,S] (transposed).
// ---------------------------------------------------------------------------
__global__ __launch_bounds__(256, 2) void gemm_qkv_kernel(
    const u16* __restrict__ Xb, const u16* __restrict__ Wtb,
    const float* __restrict__ bq, const float* __restrict__ bk,
    const float* __restrict__ bv, u16* __restrict__ Qh, u16* __restrict__ Kh,
    u16* __restrict__ Vt) {
  const int mat = blockIdx.z;
  const u16* __restrict__ Wt = Wtb + (size_t)mat * (1024u * 1024u);
  const float* __restrict__ bias = (mat == 0) ? bq : (mat == 1) ? bk : bv;

  const int m0 = blockIdx.x * 128;
  const int n0 = blockIdx.y * 128;

  __shared__ u16 As[2][128 * 64];   // [m][k] 16KB per buf, 128B rows
  __shared__ u16 Bs[2][128 * 64];   // [n][k]

  const int tid = threadIdx.x;
  const int wid = tid >> 6;
  const int lane = tid & 63;
  const int quad = lane >> 4;
  const int l16 = lane & 15;
  const int wm = (wid & 1) * 64;
  const int wn = (wid >> 1) * 64;

  const floatx4 z4 = {0.f, 0.f, 0.f, 0.f};
  floatx4 acc[4][4];
#pragma unroll
  for (int i = 0; i < 4; ++i)
#pragma unroll
    for (int j = 0; j < 4; ++j) acc[i][j] = z4;

  // staging: wave loads 32 rows A + 32 rows B; 8 rows (1KB)/call.
  const int srow = wid * 32;
  const int lrow = lane >> 3;                 // 0..7 within call
  const int gblk = (lane & 7) ^ lrow;         // xor8 swizzle

  auto stage = [&](int b, int k0) {
#pragma unroll
    for (int c = 0; c < 4; ++c) {
      const int row = srow + c * 8 + lrow;
      gld_lds16(Xb + (size_t)(m0 + row) * 1024 + k0 + gblk * 8,
                As[b] + (srow + c * 8) * 64);
      gld_lds16(Wt + (size_t)(n0 + row) * 1024 + k0 + gblk * 8,
                Bs[b] + (srow + c * 8) * 64);
    }
  };

  stage(0, 0);

  for (int i = 0; i < 16; ++i) {
    __syncthreads();                 // drains prefetch(i); frees buf (i-1)&1
    if (i < 15) stage((i + 1) & 1, (i + 1) * 64);

    const u16* __restrict__ Ab = As[i & 1];
    const u16* __restrict__ Bb = Bs[i & 1];
#pragma unroll
    for (int c = 0; c < 2; ++c) {
      const int phys = ((c * 4 + quad) ^ (l16 & 7)) * 8;
      bf16x8 af[4], bfr[4];
#pragma unroll
      for (int ii = 0; ii < 4; ++ii)
        af[ii] = *(const bf16x8*)(Ab + (wm + ii * 16 + l16) * 64 + phys);
#pragma unroll
      for (int j = 0; j < 4; ++j)
        bfr[j] = *(const bf16x8*)(Bb + (wn + j * 16 + l16) * 64 + phys);
#pragma unroll
      for (int ii = 0; ii < 4; ++ii)
#pragma unroll
        for (int j = 0; j < 4; ++j)
          acc[ii][j] = MFMA16(af[ii], bfr[j], acc[ii][j]);
    }
  }

  // epilogue. C/D layout: col = l16 (n), row = quad*4 + reg (m).
  const int b = m0 >> 10;
  const int h = n0 >> 7;
  const int sbase = (m0 & 1023) + wm;
  float bv4[4];
#pragma unroll
  for (int j = 0; j < 4; ++j) bv4[j] = bias[n0 + wn + j * 16 + l16];

  if (mat < 2) {
    u16* outp = (mat == 0 ? Qh : Kh) + (size_t)(b * 8 + h) * 1024 * 128;
#pragma unroll
    for (int i = 0; i < 4; ++i)
#pragma unroll
      for (int j = 0; j < 4; ++j) {
        const int d = wn + j * 16 + l16;
#pragma unroll
        for (int r = 0; r < 4; ++r) {
          const int s = sbase + i * 16 + quad * 4 + r;
          outp[(size_t)s * 128 + d] = f2b(acc[i][j][r] + bv4[j]);
        }
      }
  } else {
    // V^T: out[((b*8+h)*128 + d)*1024 + s]; 4 regs = 4 consecutive s.
    u16* outp = Vt + (size_t)(b * 8 + h) * 128 * 1024;
#pragma unroll
    for (int i = 0; i < 4; ++i)
#pragma unroll
      for (int j = 0; j < 4; ++j) {
        const int d = wn + j * 16 + l16;
        const int s = sbase + i * 16 + quad * 4;
        ushort4 pk;
        pk.x = f2b(acc[i][j][0] + bv4[j]);
        pk.y = f2b(acc[i][j][1] + bv4[j]);
        pk.z = f2b(acc[i][j][2] + bv4[j]);
        pk.w = f2b(acc[i][j][3] + bv4[j]);
        *(ushort4*)(outp + (size_t)d * 1024 + s) = pk;
      }
  }
}

// ---------------------------------------------------------------------------
// Kernel 3: attention (R11 structure, cvt_pk P-pack). grid 512 (2 blocks/CU
// -> 16 waves/CU = 4/SIMD), block 512 (8 waves x 16 q-rows). BQ=128, BK=64,
// K+V staged + double-buffered, ONE barrier per iteration. XCD pinning:
// xcd = id&7 owns bh in [8*xcd, 8*xcd+8) -> K/V working set 4MB = one XCD
// L2. QTMAP pairs (7,0),(5,2),(6,1),(4,3) balance CU sums.
// S^T = MFMA(kf,qf); PV per 32-key half via 1KB/wave Ps; O^T = MFMA(vf,pa).
// ---------------------------------------------------------------------------
__global__ __launch_bounds__(512, 4) void attn_kernel(const u16* __restrict__ Qh,
                                                      const u16* __restrict__ Kh,
                                                      const u16* __restrict__ Vt,
                                                      float* __restrict__ out) {
  const int id = blockIdx.x;
  const int x = id & 7;               // XCD (blocks round-robin by id%8)
  const int j = id >> 3;              // 0..63 within XCD
  const int bh = x * 8 + (j & 7);     // 8 heads pinned per XCD
  // CU-paired qt schedule: pairs (7,0),(5,2),(6,1),(4,3) -> equal work/CU.
  const int QTMAP[8] = {7, 5, 6, 4, 0, 2, 1, 3};
  const int qt = QTMAP[j >> 3];
  const int q0 = qt * 128;

  const int tid = threadIdx.x;
  const int wid = tid >> 6;           // 0..7
  const int lane = tid & 63;
  const int quad = lane >> 4;
  const int l16 = lane & 15;

  __shared__ u16 Ks[2][64 * 128];   // [key][d] 256B rows, 16KB each
  __shared__ u16 Vs[2][128 * 64];   // [d][key] 128B rows, 16KB each
  __shared__ u16 Ps[8][16 * 32];    // per-wave [q][32-key half] 64B rows, 1KB

  const u16* __restrict__ Qbase = Qh + (size_t)bh * 1024 * 128;
  const u16* __restrict__ Kbase = Kh + (size_t)bh * 1024 * 128;
  const u16* __restrict__ Vbase = Vt + (size_t)bh * 128 * 1024;

  const int qw = q0 + wid * 16;     // this wave's 16 q-rows

  // Q B-frags (for S^T = MFMA(kf,qf)): lane l16 = q, k = c*32 + quad*8.
  bf16x8 qf[4];
#pragma unroll
  for (int c = 0; c < 4; ++c)
    qf[c] = *(const bf16x8*)(Qbase + (size_t)(qw + l16) * 128 +
                             c * 32 + quad * 8);

  const floatx4 z4 = {0.f, 0.f, 0.f, 0.f};
  floatx4 o[8];
#pragma unroll
  for (int dt = 0; dt < 8; ++dt) o[dt] = z4;
  float lacc = 0.f;

  // staging (8 waves): K 64 rows x 256B -> 2 calls/wave (4 rows each);
  //                    V 128 rows x 128B -> 2 calls/wave (8 rows each).
  // Same LDS layout + swizzle invariants as R5:
  //   K: LDS[row][blk p] = src[row][p ^ (row&15)]
  //   V: LDS[row][blk p] = src[row][p ^ (row&7)]
  auto stage = [&](int b, int k0) {
#pragma unroll
    for (int c = 0; c < 2; ++c) {
      const int r0 = c * 32 + wid * 4;                 // wave's 4 K rows
      const int row = r0 + quad;
      const int sw = (wid * 4 + quad) & 15;            // row & 15
      gld_lds16(Kbase + (size_t)(k0 + row) * 128 + ((l16 ^ sw) * 8),
                Ks[b] + r0 * 128);
    }
#pragma unroll
    for (int c = 0; c < 2; ++c) {
      const int r0 = c * 64 + wid * 8;                 // wave's 8 V rows
      const int row = r0 + (lane >> 3);                // row & 7 = lane>>3 &7
      gld_lds16(Vbase + (size_t)row * 1024 + k0 +
                    (((lane & 7) ^ ((lane >> 3) & 7)) * 8),
                Vs[b] + r0 * 64);
    }
  };

  const int n = (q0 + 128) >> 6;    // 64-key iterations: 2..16
  stage(0, 0);

  for (int i = 0; i < n; ++i) {
    const int k0 = i << 6;
    __syncthreads();                // drains prefetch(i); frees buf (i-1)&1
    if (i + 1 < n) stage((i + 1) & 1, k0 + 64);

    const u16* __restrict__ Kb = Ks[i & 1];
    const u16* __restrict__ Vb = Vs[i & 1];

#pragma unroll
    for (int half = 0; half < 2; ++half) {
      if (k0 + half * 32 > qw + 15) break;   // wave-uniform causal skip

      // QK for the half's two 16-key tiles; write P into Ps.
#pragma unroll
      for (int f2 = 0; f2 < 2; ++f2) {
        const int f = half * 2 + f2;
        bf16x8 kf[4];
#pragma unroll
        for (int c = 0; c < 4; ++c)
          kf[c] = *(const bf16x8*)(Kb + (f * 16 + l16) * 128 +
                                   (((c * 4 + quad) ^ l16) * 8));
        floatx4 st = z4;
#pragma unroll
        for (int c = 0; c < 4; ++c) st = MFMA16(kf[c], qf[c], st);

        const int kb = k0 + f * 16 + quad * 4;
        const int qrow = qw + l16;
        float p[4];
#pragma unroll
        for (int r = 0; r < 4; ++r) {
          const float e = fminf(__expf(st[r] * RSCALE), 85.f);
          p[r] = (kb + r > qrow) ? 0.f : __expf(e);
        }
        lacc += (p[0] + p[1]) + (p[2] + p[3]);
        uint2 pk;
        pk.x = cvtpk_bf16(p[0], p[1]);
        pk.y = cvtpk_bf16(p[2], p[3]);
        // Ps row = l16 (64B); 16B unit u = f2*2+(quad>>1), sub = quad&1;
        // unit-swizzle u ^= (l16&3).
        *(uint2*)((char*)Ps[wid] + l16 * 64 +
                  (((f2 * 2 + (quad >> 1)) ^ (l16 & 3)) * 16) +
                  (quad & 1) * 8) = pk;
      }
      asm volatile("s_waitcnt lgkmcnt(0)" ::: "memory");  // own P visible

      // PV for this 32-key half. pa: B[k=key][n=q], lane l16=q, unit=quad^s.
      const bf16x8 pa = *(const bf16x8*)((char*)Ps[wid] + l16 * 64 +
                                         ((quad ^ (l16 & 3)) * 16));
#pragma unroll
      for (int dt = 0; dt < 8; ++dt) {
        const bf16x8 vf = *(const bf16x8*)(
            Vb + (dt * 16 + l16) * 64 +
            (((half * 4 + quad) ^ (l16 & 7)) * 8));
        o[dt] = MFMA16(vf, pa, o[dt]);
      }
    }
  }

  // l reduce across quads (lanes sharing l16), normalize, store.
  float s = lacc;
  s += __shfl_xor(s, 16);
  s += __shfl_xor(s, 32);
  const float linv = 1.0f / s;

  // O^T C-layout: col(l16)=q, row(quad*4+r)=d -> contiguous float4.
  float* outp = out + (size_t)(bh >> 3) * 1024 * 1024 + (bh & 7) * 128;
  const int qrow = qw + l16;
#pragma unroll
  for (int dt = 0; dt < 8; ++dt) {
    float4 v;
    v.x = o[dt][0] * linv;
    v.y = o[dt][1] * linv;
    v.z = o[dt][2] * linv;
    v.w = o[dt][3] * linv;
    *(float4*)(outp + (size_t)qrow * 1024 + dt * 16 + quad * 4) = v;
  }
}

// ---------------------------------------------------------------------------
extern "C" void kernel_launch(void* const* d_in, const int* in_sizes, int n_in,
                              void* d_out, int out_size, void* d_ws,
                              size_t ws_size, hipStream_t stream) {
  const float* X = (const float*)d_in[0];
  const float* Wq = (const float*)d_in[1];
  const float* bq = (const float*)d_in[2];
  const float* Wk = (const float*)d_in[3];
  const float* bk = (const float*)d_in[4];
  const float* Wv = (const float*)d_in[5];
  const float* bv = (const float*)d_in[6];
  float* out = (float*)d_out;

  char* ws = (char*)d_ws;
  u16* Xb  = (u16*)(ws);                         // 16 MB  bf16 X
  u16* Wtb = (u16*)(ws + (16u << 20));           //  6 MB  bf16 W^T x3
  u16* Qh  = (u16*)(ws + (22u << 20));           // 16 MB  [B,H,S,DH]
  u16* Kh  = (u16*)(ws + (38u << 20));           // 16 MB  [B,H,S,DH]
  u16* Vt  = (u16*)(ws + (54u << 20));           // 16 MB  [B,H,DH,S]

  prep_kernel<<<4096 + 3072, 256, 0, stream>>>((const float4*)X, Xb, Wq, Wk,
                                               Wv, Wtb);
  dim3 gg(64, 8, 3);
  gemm_qkv_kernel<<<gg, 256, 0, stream>>>(Xb, Wtb, bq, bk, bv, Qh, Kh, Vt);
  attn_kernel<<<512, 512, 0, stream>>>(Qh, Kh, Vt, out);
}

// Round 9
// 192.936 us; speedup vs baseline: 1.0013x; 1.0013x over previous
//
#include <hip/hip_runtime.h>

// ---------------------------------------------------------------------------
// ANHPMultiHeadAttention: fused QKV projection + exp-scored causal attention
// B=8, S=1024, FEAT=HID=1024, H=8, DH=128.
//
// R14: restore R12 (proven 193.2us) verbatim after R13's correctness failure.
//  - R13 post-mortem: (a) staging moved above the barrier broke R5's WAR
//    protection (fast wave DMA-writes buf (i+1)&1 while slow wave still
//    reads it) -> absmax 1.08; (b) counted vmcnt at depth-1 prefetch waits
//    on loads of the SAME age as R5's syncthreads drain (stage is issued
//    after the barrier), so the mechanism was void; depth-2 needs 96KB LDS
//    -> 1 block/CU -> occupancy loss exceeds gain (m132).
//  - Session ledger: gemm plateau 70us (depth-1 dbuf ceiling @ 2 blocks/CU);
//    attn plateau ~38us (latency chain @ 4 waves/SIMD; K+V staging proven
//    load-bearing by R8/R9). All 5 structure edits failed; R11 TLP was the
//    one win. This is the best-known-good configuration.
// ---------------------------------------------------------------------------

typedef __bf16 bf16x8 __attribute__((ext_vector_type(8)));
typedef float floatx4 __attribute__((ext_vector_type(4)));
typedef unsigned short u16;
typedef unsigned int u32;

#define RSCALE 0.08838834764831845f   // 1/sqrt(128)

__device__ __forceinline__ u16 f2b(float f) {       // fp32 -> bf16 bits, RNE
  union { float f; unsigned u; } v; v.f = f;
  return (u16)((v.u + 0x7FFFu + ((v.u >> 16) & 1u)) >> 16);
}

__device__ __forceinline__ u32 cvtpk_bf16(float lo, float hi) {
  u32 r;                               // r = bf16(lo) | bf16(hi)<<16, RNE
  asm("v_cvt_pk_bf16_f32 %0, %1, %2" : "=v"(r) : "v"(lo), "v"(hi));
  return r;
}

// async global->LDS, 16B per lane. LDS dst = wave-uniform base + lane*16.
__device__ __forceinline__ void gld_lds16(const void* g, void* l) {
  __builtin_amdgcn_global_load_lds(
      (const __attribute__((address_space(1))) unsigned*)g,
      (__attribute__((address_space(3))) unsigned*)l, 16, 0, 0);
}

#define MFMA16(a, b, c) __builtin_amdgcn_mfma_f32_16x16x32_bf16(a, b, c, 0, 0, 0)

// ---------------------------------------------------------------------------
// Kernel 1: prep = cast X (blocks 0..4095, 2 float4/thread) + transpose W
// (blocks 4096..7167)
// ---------------------------------------------------------------------------
__global__ __launch_bounds__(256) void prep_kernel(
    const float4* __restrict__ X, u16* __restrict__ Xb,
    const float* __restrict__ Wq, const float* __restrict__ Wk,
    const float* __restrict__ Wv, u16* __restrict__ Wtb) {
  if (blockIdx.x < 4096) {
#pragma unroll
    for (int rep = 0; rep < 2; ++rep) {
      unsigned i = blockIdx.x * 512u + rep * 256u + threadIdx.x;
      float4 v = X[i];
      ushort4 o;
      o.x = f2b(v.x); o.y = f2b(v.y); o.z = f2b(v.z); o.w = f2b(v.w);
      *reinterpret_cast<ushort4*>(Xb + 4u * i) = o;
    }
  } else {
    const int bid = blockIdx.x - 4096;          // 0..3071
    const int mat = bid >> 10;                  // 1024 blocks per matrix
    const int bx = bid & 31, by = (bid >> 5) & 31;
    const float* W = (mat == 0) ? Wq : (mat == 1) ? Wk : Wv;
    u16* Wt = Wtb + (size_t)mat * (1024u * 1024u);
    __shared__ u16 tile[32][33];
    const int x = threadIdx.x & 31, y = threadIdx.x >> 5;
    const int kt = bx * 32, nt = by * 32;
#pragma unroll
    for (int i = 0; i < 4; ++i)
      tile[y + 8 * i][x] = f2b(W[(size_t)(kt + y + 8 * i) * 1024 + nt + x]);
    __syncthreads();
#pragma unroll
    for (int i = 0; i < 4; ++i)
      Wt[(size_t)(nt + y + 8 * i) * 1024 + kt + x] = tile[x][y + 8 * i];
  }
}

// ---------------------------------------------------------------------------
// Kernel 2: QKV GEMM (R5-proven). 128x128 tile, BK=64 (128B rows, xor8
// swizzle, 0 conflicts), double-buffered single-barrier pipeline.
// grid (64,8,3). Q,K stored [B,H,S,DH]; V stored [B,H,DH,S] (transposed).
// The __syncthreads placement (barrier BETWEEN compute(i-1) and stage(i+1))
// is the WAR protection -- do not move staging above it (R13 failure).
// ---------------------------------------------------------------------------
__global__ __launch_bounds__(256, 2) void gemm_qkv_kernel(
    const u16* __restrict__ Xb, const u16* __restrict__ Wtb,
    const float* __restrict__ bq, const float* __restrict__ bk,
    const float* __restrict__ bv, u16* __restrict__ Qh, u16* __restrict__ Kh,
    u16* __restrict__ Vt) {
  const int mat = blockIdx.z;
  const u16* __restrict__ Wt = Wtb + (size_t)mat * (1024u * 1024u);
  const float* __restrict__ bias = (mat == 0) ? bq : (mat == 1) ? bk : bv;

  const int m0 = blockIdx.x * 128;
  const int n0 = blockIdx.y * 128;

  __shared__ u16 As[2][128 * 64];   // [m][k] 16KB per buf, 128B rows
  __shared__ u16 Bs[2][128 * 64];   // [n][k]

  const int tid = threadIdx.x;
  const int wid = tid >> 6;
  const int lane = tid & 63;
  const int quad = lane >> 4;
  const int l16 = lane & 15;
  const int wm = (wid & 1) * 64;
  const int wn = (wid >> 1) * 64;

  const floatx4 z4 = {0.f, 0.f, 0.f, 0.f};
  floatx4 acc[4][4];
#pragma unroll
  for (int i = 0; i < 4; ++i)
#pragma unroll
    for (int j = 0; j < 4; ++j) acc[i][j] = z4;

  // staging: wave loads 32 rows A + 32 rows B; 8 rows (1KB)/call.
  const int srow = wid * 32;
  const int lrow = lane >> 3;                 // 0..7 within call
  const int gblk = (lane & 7) ^ lrow;         // xor8 swizzle

  auto stage = [&](int b, int k0) {
#pragma unroll
    for (int c = 0; c < 4; ++c) {
      const int row = srow + c * 8 + lrow;
      gld_lds16(Xb + (size_t)(m0 + row) * 1024 + k0 + gblk * 8,
                As[b] + (srow + c * 8) * 64);
      gld_lds16(Wt + (size_t)(n0 + row) * 1024 + k0 + gblk * 8,
                Bs[b] + (srow + c * 8) * 64);
    }
  };

  stage(0, 0);

  for (int i = 0; i < 16; ++i) {
    __syncthreads();                 // drains prefetch(i); frees buf (i-1)&1
    if (i < 15) stage((i + 1) & 1, (i + 1) * 64);

    const u16* __restrict__ Ab = As[i & 1];
    const u16* __restrict__ Bb = Bs[i & 1];
#pragma unroll
    for (int c = 0; c < 2; ++c) {
      const int phys = ((c * 4 + quad) ^ (l16 & 7)) * 8;
      bf16x8 af[4], bfr[4];
#pragma unroll
      for (int ii = 0; ii < 4; ++ii)
        af[ii] = *(const bf16x8*)(Ab + (wm + ii * 16 + l16) * 64 + phys);
#pragma unroll
      for (int j = 0; j < 4; ++j)
        bfr[j] = *(const bf16x8*)(Bb + (wn + j * 16 + l16) * 64 + phys);
#pragma unroll
      for (int ii = 0; ii < 4; ++ii)
#pragma unroll
        for (int j = 0; j < 4; ++j)
          acc[ii][j] = MFMA16(af[ii], bfr[j], acc[ii][j]);
    }
  }

  // epilogue. C/D layout: col = l16 (n), row = quad*4 + reg (m).
  const int b = m0 >> 10;
  const int h = n0 >> 7;
  const int sbase = (m0 & 1023) + wm;
  float bv4[4];
#pragma unroll
  for (int j = 0; j < 4; ++j) bv4[j] = bias[n0 + wn + j * 16 + l16];

  if (mat < 2) {
    u16* outp = (mat == 0 ? Qh : Kh) + (size_t)(b * 8 + h) * 1024 * 128;
#pragma unroll
    for (int i = 0; i < 4; ++i)
#pragma unroll
      for (int j = 0; j < 4; ++j) {
        const int d = wn + j * 16 + l16;
#pragma unroll
        for (int r = 0; r < 4; ++r) {
          const int s = sbase + i * 16 + quad * 4 + r;
          outp[(size_t)s * 128 + d] = f2b(acc[i][j][r] + bv4[j]);
        }
      }
  } else {
    // V^T: out[((b*8+h)*128 + d)*1024 + s]; 4 regs = 4 consecutive s.
    u16* outp = Vt + (size_t)(b * 8 + h) * 128 * 1024;
#pragma unroll
    for (int i = 0; i < 4; ++i)
#pragma unroll
      for (int j = 0; j < 4; ++j) {
        const int d = wn + j * 16 + l16;
        const int s = sbase + i * 16 + quad * 4;
        ushort4 pk;
        pk.x = f2b(acc[i][j][0] + bv4[j]);
        pk.y = f2b(acc[i][j][1] + bv4[j]);
        pk.z = f2b(acc[i][j][2] + bv4[j]);
        pk.w = f2b(acc[i][j][3] + bv4[j]);
        *(ushort4*)(outp + (size_t)d * 1024 + s) = pk;
      }
  }
}

// ---------------------------------------------------------------------------
// Kernel 3: attention (R11 structure, cvt_pk P-pack). grid 512 (2 blocks/CU
// -> 16 waves/CU = 4/SIMD), block 512 (8 waves x 16 q-rows). BQ=128, BK=64,
// K+V staged + double-buffered, ONE barrier per iteration. XCD pinning:
// xcd = id&7 owns bh in [8*xcd, 8*xcd+8) -> K/V working set 4MB = one XCD
// L2. QTMAP pairs (7,0),(5,2),(6,1),(4,3) balance CU sums.
// S^T = MFMA(kf,qf); PV per 32-key half via 1KB/wave Ps; O^T = MFMA(vf,pa).
// ---------------------------------------------------------------------------
__global__ __launch_bounds__(512, 4) void attn_kernel(const u16* __restrict__ Qh,
                                                      const u16* __restrict__ Kh,
                                                      const u16* __restrict__ Vt,
                                                      float* __restrict__ out) {
  const int id = blockIdx.x;
  const int x = id & 7;               // XCD (blocks round-robin by id%8)
  const int j = id >> 3;              // 0..63 within XCD
  const int bh = x * 8 + (j & 7);     // 8 heads pinned per XCD
  // CU-paired qt schedule: pairs (7,0),(5,2),(6,1),(4,3) -> equal work/CU.
  const int QTMAP[8] = {7, 5, 6, 4, 0, 2, 1, 3};
  const int qt = QTMAP[j >> 3];
  const int q0 = qt * 128;

  const int tid = threadIdx.x;
  const int wid = tid >> 6;           // 0..7
  const int lane = tid & 63;
  const int quad = lane >> 4;
  const int l16 = lane & 15;

  __shared__ u16 Ks[2][64 * 128];   // [key][d] 256B rows, 16KB each
  __shared__ u16 Vs[2][128 * 64];   // [d][key] 128B rows, 16KB each
  __shared__ u16 Ps[8][16 * 32];    // per-wave [q][32-key half] 64B rows, 1KB

  const u16* __restrict__ Qbase = Qh + (size_t)bh * 1024 * 128;
  const u16* __restrict__ Kbase = Kh + (size_t)bh * 1024 * 128;
  const u16* __restrict__ Vbase = Vt + (size_t)bh * 128 * 1024;

  const int qw = q0 + wid * 16;     // this wave's 16 q-rows

  // Q B-frags (for S^T = MFMA(kf,qf)): lane l16 = q, k = c*32 + quad*8.
  bf16x8 qf[4];
#pragma unroll
  for (int c = 0; c < 4; ++c)
    qf[c] = *(const bf16x8*)(Qbase + (size_t)(qw + l16) * 128 +
                             c * 32 + quad * 8);

  const floatx4 z4 = {0.f, 0.f, 0.f, 0.f};
  floatx4 o[8];
#pragma unroll
  for (int dt = 0; dt < 8; ++dt) o[dt] = z4;
  float lacc = 0.f;

  // staging (8 waves): K 64 rows x 256B -> 2 calls/wave (4 rows each);
  //                    V 128 rows x 128B -> 2 calls/wave (8 rows each).
  // Same LDS layout + swizzle invariants as R5:
  //   K: LDS[row][blk p] = src[row][p ^ (row&15)]
  //   V: LDS[row][blk p] = src[row][p ^ (row&7)]
  auto stage = [&](int b, int k0) {
#pragma unroll
    for (int c = 0; c < 2; ++c) {
      const int r0 = c * 32 + wid * 4;                 // wave's 4 K rows
      const int row = r0 + quad;
      const int sw = (wid * 4 + quad) & 15;            // row & 15
      gld_lds16(Kbase + (size_t)(k0 + row) * 128 + ((l16 ^ sw) * 8),
                Ks[b] + r0 * 128);
    }
#pragma unroll
    for (int c = 0; c < 2; ++c) {
      const int r0 = c * 64 + wid * 8;                 // wave's 8 V rows
      const int row = r0 + (lane >> 3);                // row & 7 = lane>>3 &7
      gld_lds16(Vbase + (size_t)row * 1024 + k0 +
                    (((lane & 7) ^ ((lane >> 3) & 7)) * 8),
                Vs[b] + r0 * 64);
    }
  };

  const int n = (q0 + 128) >> 6;    // 64-key iterations: 2..16
  stage(0, 0);

  for (int i = 0; i < n; ++i) {
    const int k0 = i << 6;
    __syncthreads();                // drains prefetch(i); frees buf (i-1)&1
    if (i + 1 < n) stage((i + 1) & 1, k0 + 64);

    const u16* __restrict__ Kb = Ks[i & 1];
    const u16* __restrict__ Vb = Vs[i & 1];

#pragma unroll
    for (int half = 0; half < 2; ++half) {
      if (k0 + half * 32 > qw + 15) break;   // wave-uniform causal skip

      // QK for the half's two 16-key tiles; write P into Ps.
#pragma unroll
      for (int f2 = 0; f2 < 2; ++f2) {
        const int f = half * 2 + f2;
        bf16x8 kf[4];
#pragma unroll
        for (int c = 0; c < 4; ++c)
          kf[c] = *(const bf16x8*)(Kb + (f * 16 + l16) * 128 +
                                   (((c * 4 + quad) ^ l16) * 8));
        floatx4 st = z4;
#pragma unroll
        for (int c = 0; c < 4; ++c) st = MFMA16(kf[c], qf[c], st);

        const int kb = k0 + f * 16 + quad * 4;
        const int qrow = qw + l16;
        float p[4];
#pragma unroll
        for (int r = 0; r < 4; ++r) {
          const float e = fminf(__expf(st[r] * RSCALE), 85.f);
          p[r] = (kb + r > qrow) ? 0.f : __expf(e);
        }
        lacc += (p[0] + p[1]) + (p[2] + p[3]);
        uint2 pk;
        pk.x = cvtpk_bf16(p[0], p[1]);
        pk.y = cvtpk_bf16(p[2], p[3]);
        // Ps row = l16 (64B); 16B unit u = f2*2+(quad>>1), sub = quad&1;
        // unit-swizzle u ^= (l16&3).
        *(uint2*)((char*)Ps[wid] + l16 * 64 +
                  (((f2 * 2 + (quad >> 1)) ^ (l16 & 3)) * 16) +
                  (quad & 1) * 8) = pk;
      }
      asm volatile("s_waitcnt lgkmcnt(0)" ::: "memory");  // own P visible

      // PV for this 32-key half. pa: B[k=key][n=q], lane l16=q, unit=quad^s.
      const bf16x8 pa = *(const bf16x8*)((char*)Ps[wid] + l16 * 64 +
                                         ((quad ^ (l16 & 3)) * 16));
#pragma unroll
      for (int dt = 0; dt < 8; ++dt) {
        const bf16x8 vf = *(const bf16x8*)(
            Vb + (dt * 16 + l16) * 64 +
            (((half * 4 + quad) ^ (l16 & 7)) * 8));
        o[dt] = MFMA16(vf, pa, o[dt]);
      }
    }
  }

  // l reduce across quads (lanes sharing l16), normalize, store.
  float s = lacc;
  s += __shfl_xor(s, 16);
  s += __shfl_xor(s, 32);
  const float linv = 1.0f / s;

  // O^T C-layout: col(l16)=q, row(quad*4+r)=d -> contiguous float4.
  float* outp = out + (size_t)(bh >> 3) * 1024 * 1024 + (bh & 7) * 128;
  const int qrow = qw + l16;
#pragma unroll
  for (int dt = 0; dt < 8; ++dt) {
    float4 v;
    v.x = o[dt][0] * linv;
    v.y = o[dt][1] * linv;
    v.z = o[dt][2] * linv;
    v.w = o[dt][3] * linv;
    *(float4*)(outp + (size_t)qrow * 1024 + dt * 16 + quad * 4) = v;
  }
}

// ---------------------------------------------------------------------------
extern "C" void kernel_launch(void* const* d_in, const int* in_sizes, int n_in,
                              void* d_out, int out_size, void* d_ws,
                              size_t ws_size, hipStream_t stream) {
  const float* X = (const float*)d_in[0];
  const float* Wq = (const float*)d_in[1];
  const float* bq = (const float*)d_in[2];
  const float* Wk = (const float*)d_in[3];
  const float* bk = (const float*)d_in[4];
  const float* Wv = (const float*)d_in[5];
  const float* bv = (const float*)d_in[6];
  float* out = (float*)d_out;

  char* ws = (char*)d_ws;
  u16* Xb  = (u16*)(ws);                         // 16 MB  bf16 X
  u16* Wtb = (u16*)(ws + (16u << 20));           //  6 MB  bf16 W^T x3
  u16* Qh  = (u16*)(ws + (22u << 20));           // 16 MB  [B,H,S,DH]
  u16* Kh  = (u16*)(ws + (38u << 20));           // 16 MB  [B,H,S,DH]
  u16* Vt  = (u16*)(ws + (54u << 20));           // 16 MB  [B,H,DH,S]

  prep_kernel<<<4096 + 3072, 256, 0, stream>>>((const float4*)X, Xb, Wq, Wk,
                                               Wv, Wtb);
  dim3 gg(64, 8, 3);
  gemm_qkv_kernel<<<gg, 256, 0, stream>>>(Xb, Wtb, bq, bk, bv, Qh, Kh, Vt);
  attn_kernel<<<512, 512, 0, stream>>>(Qh, Kh, Vt, out);
}

// Round 10
// 192.114 us; speedup vs baseline: 1.0056x; 1.0043x over previous
//
#include <hip/hip_runtime.h>

// ---------------------------------------------------------------------------
// ANHPMultiHeadAttention: fused QKV projection + exp-scored causal attention
// B=8, S=1024, FEAT=HID=1024, H=8, DH=128.
//
// R15 changes vs R14 (192.9us best):
//  - prep ONLY. W-transpose was issue-bound: 32x32 tiles, 16 scalar f32
//    loads + 16 scalar u16 LDS ops + 16 scalar u16 global stores per
//    thread. Now 64x64 tiles (768 blocks, placed FIRST to overlap the
//    BW-bound cast blocks): float4 loads, LDS [64][68] u16 (pad-68: 136B
//    row stride -> b64-aligned, read-side conflict-free; write-side 4-way
//    on 4 tiny b16 writes), ushort4 stores -> 4x fewer memory insts.
//    Cast part packs via cvtpk_bf16 (bit-identical bytes, proven in attn).
//  - GEMM / attn: R14 byte-identical (controls; gemm 67.7-73.5 noise band,
//    MfmaUtil ~30, conflicts 0; attn parked at latency floor, sub-top-5).
// ---------------------------------------------------------------------------

typedef __bf16 bf16x8 __attribute__((ext_vector_type(8)));
typedef float floatx4 __attribute__((ext_vector_type(4)));
typedef unsigned short u16;
typedef unsigned int u32;

#define RSCALE 0.08838834764831845f   // 1/sqrt(128)

__device__ __forceinline__ u16 f2b(float f) {       // fp32 -> bf16 bits, RNE
  union { float f; unsigned u; } v; v.f = f;
  return (u16)((v.u + 0x7FFFu + ((v.u >> 16) & 1u)) >> 16);
}

__device__ __forceinline__ u32 cvtpk_bf16(float lo, float hi) {
  u32 r;                               // r = bf16(lo) | bf16(hi)<<16, RNE
  asm("v_cvt_pk_bf16_f32 %0, %1, %2" : "=v"(r) : "v"(lo), "v"(hi));
  return r;
}

// async global->LDS, 16B per lane. LDS dst = wave-uniform base + lane*16.
__device__ __forceinline__ void gld_lds16(const void* g, void* l) {
  __builtin_amdgcn_global_load_lds(
      (const __attribute__((address_space(1))) unsigned*)g,
      (__attribute__((address_space(3))) unsigned*)l, 16, 0, 0);
}

#define MFMA16(a, b, c) __builtin_amdgcn_mfma_f32_16x16x32_bf16(a, b, c, 0, 0, 0)

// ---------------------------------------------------------------------------
// Kernel 1: prep. Blocks 0..767: transpose W (64x64 tiles, vectorized).
// Blocks 768..4863: cast X (2 float4/thread).
// ---------------------------------------------------------------------------
__global__ __launch_bounds__(256) void prep_kernel(
    const float4* __restrict__ X, u16* __restrict__ Xb,
    const float* __restrict__ Wq, const float* __restrict__ Wk,
    const float* __restrict__ Wv, u16* __restrict__ Wtb) {
  if (blockIdx.x < 768) {
    // --- W transpose: 64x64 tile per block, 256 per matrix.
    const int bid = blockIdx.x;
    const int mat = bid >> 8;                   // 256 blocks per matrix
    const int t = bid & 255;
    const int kt = (t & 15) * 64;               // k-tile base
    const int nt = (t >> 4) * 64;               // n-tile base
    const float* W = (mat == 0) ? Wq : (mat == 1) ? Wk : Wv;
    u16* Wt = Wtb + (size_t)mat * (1024u * 1024u);

    __shared__ u16 tile[64][68];                // [n][k], pad-68 (136B rows)
    const int x = threadIdx.x & 15;             // 0..15
    const int y = threadIdx.x >> 4;             // 0..15

    // load: float4 along n (4 consecutive n for fixed k); 4 passes over k.
#pragma unroll
    for (int p = 0; p < 4; ++p) {
      const int k = p * 16 + y;                 // 0..63 within tile
      const float4 v = *(const float4*)(W + (size_t)(kt + k) * 1024 + nt + 4 * x);
      tile[4 * x + 0][k] = f2b(v.x);
      tile[4 * x + 1][k] = f2b(v.y);
      tile[4 * x + 2][k] = f2b(v.z);
      tile[4 * x + 3][k] = f2b(v.w);
    }
    __syncthreads();
    // store: ushort4 along k (contiguous); 4 passes over n.
#pragma unroll
    for (int p = 0; p < 4; ++p) {
      const int nr = p * 16 + y;                // 0..63 within tile
      const ushort4 q = *(const ushort4*)&tile[nr][4 * x];
      *(ushort4*)(Wt + (size_t)(nt + nr) * 1024 + kt + 4 * x) = q;
    }
  } else {
    // --- X cast: 2 float4 per thread.
    const unsigned cb = blockIdx.x - 768;
#pragma unroll
    for (int rep = 0; rep < 2; ++rep) {
      unsigned i = cb * 512u + rep * 256u + threadIdx.x;
      float4 v = X[i];
      uint2 o;
      o.x = cvtpk_bf16(v.x, v.y);
      o.y = cvtpk_bf16(v.z, v.w);
      *reinterpret_cast<uint2*>(Xb + 4u * i) = o;
    }
  }
}

// ---------------------------------------------------------------------------
// Kernel 2: QKV GEMM (R5-proven). 128x128 tile, BK=64 (128B rows, xor8
// swizzle, 0 conflicts), double-buffered single-barrier pipeline.
// grid (64,8,3). Q,K stored [B,H,S,DH]; V stored [B,H,DH,S] (transposed).
// The __syncthreads placement (barrier BETWEEN compute(i-1) and stage(i+1))
// is the WAR protection -- do not move staging above it (R13 failure).
// ---------------------------------------------------------------------------
__global__ __launch_bounds__(256, 2) void gemm_qkv_kernel(
    const u16* __restrict__ Xb, const u16* __restrict__ Wtb,
    const float* __restrict__ bq, const float* __restrict__ bk,
    const float* __restrict__ bv, u16* __restrict__ Qh, u16* __restrict__ Kh,
    u16* __restrict__ Vt) {
  const int mat = blockIdx.z;
  const u16* __restrict__ Wt = Wtb + (size_t)mat * (1024u * 1024u);
  const float* __restrict__ bias = (mat == 0) ? bq : (mat == 1) ? bk : bv;

  const int m0 = blockIdx.x * 128;
  const int n0 = blockIdx.y * 128;

  __shared__ u16 As[2][128 * 64];   // [m][k] 16KB per buf, 128B rows
  __shared__ u16 Bs[2][128 * 64];   // [n][k]

  const int tid = threadIdx.x;
  const int wid = tid >> 6;
  const int lane = tid & 63;
  const int quad = lane >> 4;
  const int l16 = lane & 15;
  const int wm = (wid & 1) * 64;
  const int wn = (wid >> 1) * 64;

  const floatx4 z4 = {0.f, 0.f, 0.f, 0.f};
  floatx4 acc[4][4];
#pragma unroll
  for (int i = 0; i < 4; ++i)
#pragma unroll
    for (int j = 0; j < 4; ++j) acc[i][j] = z4;

  // staging: wave loads 32 rows A + 32 rows B; 8 rows (1KB)/call.
  const int srow = wid * 32;
  const int lrow = lane >> 3;                 // 0..7 within call
  const int gblk = (lane & 7) ^ lrow;         // xor8 swizzle

  auto stage = [&](int b, int k0) {
#pragma unroll
    for (int c = 0; c < 4; ++c) {
      const int row = srow + c * 8 + lrow;
      gld_lds16(Xb + (size_t)(m0 + row) * 1024 + k0 + gblk * 8,
                As[b] + (srow + c * 8) * 64);
      gld_lds16(Wt + (size_t)(n0 + row) * 1024 + k0 + gblk * 8,
                Bs[b] + (srow + c * 8) * 64);
    }
  };

  stage(0, 0);

  for (int i = 0; i < 16; ++i) {
    __syncthreads();                 // drains prefetch(i); frees buf (i-1)&1
    if (i < 15) stage((i + 1) & 1, (i + 1) * 64);

    const u16* __restrict__ Ab = As[i & 1];
    const u16* __restrict__ Bb = Bs[i & 1];
#pragma unroll
    for (int c = 0; c < 2; ++c) {
      const int phys = ((c * 4 + quad) ^ (l16 & 7)) * 8;
      bf16x8 af[4], bfr[4];
#pragma unroll
      for (int ii = 0; ii < 4; ++ii)
        af[ii] = *(const bf16x8*)(Ab + (wm + ii * 16 + l16) * 64 + phys);
#pragma unroll
      for (int j = 0; j < 4; ++j)
        bfr[j] = *(const bf16x8*)(Bb + (wn + j * 16 + l16) * 64 + phys);
#pragma unroll
      for (int ii = 0; ii < 4; ++ii)
#pragma unroll
        for (int j = 0; j < 4; ++j)
          acc[ii][j] = MFMA16(af[ii], bfr[j], acc[ii][j]);
    }
  }

  // epilogue. C/D layout: col = l16 (n), row = quad*4 + reg (m).
  const int b = m0 >> 10;
  const int h = n0 >> 7;
  const int sbase = (m0 & 1023) + wm;
  float bv4[4];
#pragma unroll
  for (int j = 0; j < 4; ++j) bv4[j] = bias[n0 + wn + j * 16 + l16];

  if (mat < 2) {
    u16* outp = (mat == 0 ? Qh : Kh) + (size_t)(b * 8 + h) * 1024 * 128;
#pragma unroll
    for (int i = 0; i < 4; ++i)
#pragma unroll
      for (int j = 0; j < 4; ++j) {
        const int d = wn + j * 16 + l16;
#pragma unroll
        for (int r = 0; r < 4; ++r) {
          const int s = sbase + i * 16 + quad * 4 + r;
          outp[(size_t)s * 128 + d] = f2b(acc[i][j][r] + bv4[j]);
        }
      }
  } else {
    // V^T: out[((b*8+h)*128 + d)*1024 + s]; 4 regs = 4 consecutive s.
    u16* outp = Vt + (size_t)(b * 8 + h) * 128 * 1024;
#pragma unroll
    for (int i = 0; i < 4; ++i)
#pragma unroll
      for (int j = 0; j < 4; ++j) {
        const int d = wn + j * 16 + l16;
        const int s = sbase + i * 16 + quad * 4;
        ushort4 pk;
        pk.x = f2b(acc[i][j][0] + bv4[j]);
        pk.y = f2b(acc[i][j][1] + bv4[j]);
        pk.z = f2b(acc[i][j][2] + bv4[j]);
        pk.w = f2b(acc[i][j][3] + bv4[j]);
        *(ushort4*)(outp + (size_t)d * 1024 + s) = pk;
      }
  }
}

// ---------------------------------------------------------------------------
// Kernel 3: attention (R11 structure, cvt_pk P-pack). grid 512 (2 blocks/CU
// -> 16 waves/CU = 4/SIMD), block 512 (8 waves x 16 q-rows). BQ=128, BK=64,
// K+V staged + double-buffered, ONE barrier per iteration. XCD pinning:
// xcd = id&7 owns bh in [8*xcd, 8*xcd+8) -> K/V working set 4MB = one XCD
// L2. QTMAP pairs (7,0),(5,2),(6,1),(4,3) balance CU sums.
// S^T = MFMA(kf,qf); PV per 32-key half via 1KB/wave Ps; O^T = MFMA(vf,pa).
// ---------------------------------------------------------------------------
__global__ __launch_bounds__(512, 4) void attn_kernel(const u16* __restrict__ Qh,
                                                      const u16* __restrict__ Kh,
                                                      const u16* __restrict__ Vt,
                                                      float* __restrict__ out) {
  const int id = blockIdx.x;
  const int x = id & 7;               // XCD (blocks round-robin by id%8)
  const int j = id >> 3;              // 0..63 within XCD
  const int bh = x * 8 + (j & 7);     // 8 heads pinned per XCD
  // CU-paired qt schedule: pairs (7,0),(5,2),(6,1),(4,3) -> equal work/CU.
  const int QTMAP[8] = {7, 5, 6, 4, 0, 2, 1, 3};
  const int qt = QTMAP[j >> 3];
  const int q0 = qt * 128;

  const int tid = threadIdx.x;
  const int wid = tid >> 6;           // 0..7
  const int lane = tid & 63;
  const int quad = lane >> 4;
  const int l16 = lane & 15;

  __shared__ u16 Ks[2][64 * 128];   // [key][d] 256B rows, 16KB each
  __shared__ u16 Vs[2][128 * 64];   // [d][key] 128B rows, 16KB each
  __shared__ u16 Ps[8][16 * 32];    // per-wave [q][32-key half] 64B rows, 1KB

  const u16* __restrict__ Qbase = Qh + (size_t)bh * 1024 * 128;
  const u16* __restrict__ Kbase = Kh + (size_t)bh * 1024 * 128;
  const u16* __restrict__ Vbase = Vt + (size_t)bh * 128 * 1024;

  const int qw = q0 + wid * 16;     // this wave's 16 q-rows

  // Q B-frags (for S^T = MFMA(kf,qf)): lane l16 = q, k = c*32 + quad*8.
  bf16x8 qf[4];
#pragma unroll
  for (int c = 0; c < 4; ++c)
    qf[c] = *(const bf16x8*)(Qbase + (size_t)(qw + l16) * 128 +
                             c * 32 + quad * 8);

  const floatx4 z4 = {0.f, 0.f, 0.f, 0.f};
  floatx4 o[8];
#pragma unroll
  for (int dt = 0; dt < 8; ++dt) o[dt] = z4;
  float lacc = 0.f;

  // staging (8 waves): K 64 rows x 256B -> 2 calls/wave (4 rows each);
  //                    V 128 rows x 128B -> 2 calls/wave (8 rows each).
  // Same LDS layout + swizzle invariants as R5:
  //   K: LDS[row][blk p] = src[row][p ^ (row&15)]
  //   V: LDS[row][blk p] = src[row][p ^ (row&7)]
  auto stage = [&](int b, int k0) {
#pragma unroll
    for (int c = 0; c < 2; ++c) {
      const int r0 = c * 32 + wid * 4;                 // wave's 4 K rows
      const int row = r0 + quad;
      const int sw = (wid * 4 + quad) & 15;            // row & 15
      gld_lds16(Kbase + (size_t)(k0 + row) * 128 + ((l16 ^ sw) * 8),
                Ks[b] + r0 * 128);
    }
#pragma unroll
    for (int c = 0; c < 2; ++c) {
      const int r0 = c * 64 + wid * 8;                 // wave's 8 V rows
      const int row = r0 + (lane >> 3);                // row & 7 = lane>>3 &7
      gld_lds16(Vbase + (size_t)row * 1024 + k0 +
                    (((lane & 7) ^ ((lane >> 3) & 7)) * 8),
                Vs[b] + r0 * 64);
    }
  };

  const int n = (q0 + 128) >> 6;    // 64-key iterations: 2..16
  stage(0, 0);

  for (int i = 0; i < n; ++i) {
    const int k0 = i << 6;
    __syncthreads();                // drains prefetch(i); frees buf (i-1)&1
    if (i + 1 < n) stage((i + 1) & 1, k0 + 64);

    const u16* __restrict__ Kb = Ks[i & 1];
    const u16* __restrict__ Vb = Vs[i & 1];

#pragma unroll
    for (int half = 0; half < 2; ++half) {
      if (k0 + half * 32 > qw + 15) break;   // wave-uniform causal skip

      // QK for the half's two 16-key tiles; write P into Ps.
#pragma unroll
      for (int f2 = 0; f2 < 2; ++f2) {
        const int f = half * 2 + f2;
        bf16x8 kf[4];
#pragma unroll
        for (int c = 0; c < 4; ++c)
          kf[c] = *(const bf16x8*)(Kb + (f * 16 + l16) * 128 +
                                   (((c * 4 + quad) ^ l16) * 8));
        floatx4 st = z4;
#pragma unroll
        for (int c = 0; c < 4; ++c) st = MFMA16(kf[c], qf[c], st);

        const int kb = k0 + f * 16 + quad * 4;
        const int qrow = qw + l16;
        float p[4];
#pragma unroll
        for (int r = 0; r < 4; ++r) {
          const float e = fminf(__expf(st[r] * RSCALE), 85.f);
          p[r] = (kb + r > qrow) ? 0.f : __expf(e);
        }
        lacc += (p[0] + p[1]) + (p[2] + p[3]);
        uint2 pk;
        pk.x = cvtpk_bf16(p[0], p[1]);
        pk.y = cvtpk_bf16(p[2], p[3]);
        // Ps row = l16 (64B); 16B unit u = f2*2+(quad>>1), sub = quad&1;
        // unit-swizzle u ^= (l16&3).
        *(uint2*)((char*)Ps[wid] + l16 * 64 +
                  (((f2 * 2 + (quad >> 1)) ^ (l16 & 3)) * 16) +
                  (quad & 1) * 8) = pk;
      }
      asm volatile("s_waitcnt lgkmcnt(0)" ::: "memory");  // own P visible

      // PV for this 32-key half. pa: B[k=key][n=q], lane l16=q, unit=quad^s.
      const bf16x8 pa = *(const bf16x8*)((char*)Ps[wid] + l16 * 64 +
                                         ((quad ^ (l16 & 3)) * 16));
#pragma unroll
      for (int dt = 0; dt < 8; ++dt) {
        const bf16x8 vf = *(const bf16x8*)(
            Vb + (dt * 16 + l16) * 64 +
            (((half * 4 + quad) ^ (l16 & 7)) * 8));
        o[dt] = MFMA16(vf, pa, o[dt]);
      }
    }
  }

  // l reduce across quads (lanes sharing l16), normalize, store.
  float s = lacc;
  s += __shfl_xor(s, 16);
  s += __shfl_xor(s, 32);
  const float linv = 1.0f / s;

  // O^T C-layout: col(l16)=q, row(quad*4+r)=d -> contiguous float4.
  float* outp = out + (size_t)(bh >> 3) * 1024 * 1024 + (bh & 7) * 128;
  const int qrow = qw + l16;
#pragma unroll
  for (int dt = 0; dt < 8; ++dt) {
    float4 v;
    v.x = o[dt][0] * linv;
    v.y = o[dt][1] * linv;
    v.z = o[dt][2] * linv;
    v.w = o[dt][3] * linv;
    *(float4*)(outp + (size_t)qrow * 1024 + dt * 16 + quad * 4) = v;
  }
}

// ---------------------------------------------------------------------------
extern "C" void kernel_launch(void* const* d_in, const int* in_sizes, int n_in,
                              void* d_out, int out_size, void* d_ws,
                              size_t ws_size, hipStream_t stream) {
  const float* X = (const float*)d_in[0];
  const float* Wq = (const float*)d_in[1];
  const float* bq = (const float*)d_in[2];
  const float* Wk = (const float*)d_in[3];
  const float* bk = (const float*)d_in[4];
  const float* Wv = (const float*)d_in[5];
  const float* bv = (const float*)d_in[6];
  float* out = (float*)d_out;

  char* ws = (char*)d_ws;
  u16* Xb  = (u16*)(ws);                         // 16 MB  bf16 X
  u16* Wtb = (u16*)(ws + (16u << 20));           //  6 MB  bf16 W^T x3
  u16* Qh  = (u16*)(ws + (22u << 20));           // 16 MB  [B,H,S,DH]
  u16* Kh  = (u16*)(ws + (38u << 20));           // 16 MB  [B,H,S,DH]
  u16* Vt  = (u16*)(ws + (54u << 20));           // 16 MB  [B,H,DH,S]

  prep_kernel<<<768 + 4096, 256, 0, stream>>>((const float4*)X, Xb, Wq, Wk,
                                              Wv, Wtb);
  dim3 gg(64, 8, 3);
  gemm_qkv_kernel<<<gg, 256, 0, stream>>>(Xb, Wtb, bq, bk, bv, Qh, Kh, Vt);
  attn_kernel<<<512, 512, 0, stream>>>(Qh, Kh, Vt, out);
}